// Round 7
// baseline (135.377 us; speedup 1.0000x reference)
//
#include <hip/hip_runtime.h>

#define NDIM 80
#define NB 6400            // batches; also elements per batch matrix
#define GRID 512           // persistent blocks: 2 per CU
#define TOL 0.01f
#define MAXIT 101

typedef const __attribute__((address_space(1))) void* gas_ptr;
typedef __attribute__((address_space(3))) void* las_ptr;

// Raw barrier: drain LDS ops only — NEVER vmcnt (prefetch stays in flight).
#define BARRIER() do { \
    asm volatile("s_waitcnt lgkmcnt(0)" ::: "memory"); \
    __builtin_amdgcn_s_barrier(); \
    asm volatile("" ::: "memory"); \
} while (0)

// Issue batch BB's 15 vmem ops: 5 global_load_lds (rc -> Ms[C], each wave's
// own 5KB region) + 10 coalesced dwordx4 (rz, wr -> named reg set).
#define ISSUE(BB, C, RA, WA) do { \
    const size_t base_ = (size_t)(BB) * NB; \
    _Pragma("unroll") \
    for (int ch_ = 0; ch_ < 5; ++ch_) { \
        const int foff_ = (wv * 5 + ch_) * 256; \
        __builtin_amdgcn_global_load_lds((gas_ptr)(r_const + base_ + foff_ + lane * 4), \
                                         (las_ptr)&Ms[C][foff_], 16, 0, 0); \
    } \
    const float4* rz4_ = reinterpret_cast<const float4*>(r_zeros + base_); \
    const float4* wr4_ = reinterpret_cast<const float4*>(weights_r + base_); \
    _Pragma("unroll") \
    for (int u_ = 0; u_ < 5; ++u_) { \
        RA[u_] = rz4_[t + 320 * u_]; \
        WA[u_] = wr4_[t + 320 * u_]; \
    } \
} while (0)

// M = rc + wr*rz in place; each lane RMWs exactly the quads its own wave's
// global_load_lds wrote -> no cross-wave hazard before the barrier.
#define BUILD(C, RA, WA) do { \
    _Pragma("unroll") \
    for (int u_ = 0; u_ < 5; ++u_) { \
        float4* p4_ = reinterpret_cast<float4*>(&Ms[C][1280 * wv + 256 * u_ + 4 * lane]); \
        float4 cc_ = *p4_; \
        cc_.x = fmaf(WA[u_].x, RA[u_].x, cc_.x); \
        cc_.y = fmaf(WA[u_].y, RA[u_].y, cc_.y); \
        cc_.z = fmaf(WA[u_].z, RA[u_].z, cc_.z); \
        cc_.w = fmaf(WA[u_].w, RA[u_].w, cc_.w); \
        *p4_ = cc_; \
    } \
    if (t < NDIM) av[t] = 1.0f; \
    BARRIER(); \
} while (0)

// Power iteration (R4/R6-verified math, absmax 0.0) + per-batch epilogue.
#define POWER_EPI(BB, C) do { \
    const float4* Mr4_ = reinterpret_cast<const float4*>(&Ms[C][r * NDIM + vq]); \
    const float4* vv4_ = reinterpret_cast<const float4*>(&v[vq]); \
    float n2_ = (float)NDIM; \
    float ev_ = 1e30f; \
    for (int it_ = 0; it_ < MAXIT; ++it_) { \
        const float inv_ = rsqrtf(n2_); \
        if (t < NDIM) v[t] = av[t] * inv_; \
        BARRIER(); \
        float p_ = 0.f; \
        _Pragma("unroll") \
        for (int u_ = 0; u_ < 5; ++u_) { \
            const float4 mm_ = Mr4_[u_]; \
            const float4 xv_ = vv4_[u_]; \
            p_ = fmaf(mm_.x, xv_.x, p_); \
            p_ = fmaf(mm_.y, xv_.y, p_); \
            p_ = fmaf(mm_.z, xv_.z, p_); \
            p_ = fmaf(mm_.w, xv_.w, p_); \
        } \
        p_ += __shfl_xor(p_, 1); \
        p_ += __shfl_xor(p_, 2); \
        if (q == 0) av[r] = p_; \
        BARRIER(); \
        if (t < 64) { \
            float a0_ = av[t], v0_ = v[t]; \
            float s2_ = a0_ * a0_; \
            float sd_ = v0_ * a0_; \
            if (t < 16) { \
                float a1_ = av[t + 64], v1_ = v[t + 64]; \
                s2_ = fmaf(a1_, a1_, s2_); \
                sd_ = fmaf(v1_, a1_, sd_); \
            } \
            _Pragma("unroll") \
            for (int o_ = 32; o_ > 0; o_ >>= 1) { \
                s2_ += __shfl_down(s2_, o_); \
                sd_ += __shfl_down(sd_, o_); \
            } \
            if (t == 0) { red[0] = s2_; red[1] = sd_; } \
        } \
        BARRIER(); \
        n2_ = red[0]; \
        const float evn_ = red[1]; \
        if (fabsf(ev_ - evn_) < TOL) break; \
        ev_ = evn_; \
    } \
    if (t == 0) { \
        const size_t base_ = (size_t)(BB) * NB; \
        const int ii_ = (BB) / NDIM; \
        const float rcd_ = r_const[base_ + (size_t)ii_ * (NDIM + 1)]; \
        sscale = x[BB] * weights_t[BB] * rcd_ / v[ii_]; \
    } \
    BARRIER(); \
    if (t < NDIM) contrib[(size_t)(BB) * NDIM + t] = v[t] * sscale; \
} while (0)

__global__ __launch_bounds__(320, 3) void fused_power_kernel(
    const float* __restrict__ x,
    const float* __restrict__ r_zeros,
    const float* __restrict__ r_const,
    const float* __restrict__ weights_t,
    const float* __restrict__ weights_r,
    float* __restrict__ contrib)
{
    __shared__ float Ms[2][NB];   // 51.2 KB double buffer
    __shared__ float v[NDIM];
    __shared__ float av[NDIM];
    __shared__ float red[2];
    __shared__ float sscale;

    const int t    = threadIdx.x;
    const int wv   = t >> 6;
    const int lane = t & 63;
    const int r    = t >> 2;
    const int q    = t & 3;
    const int vq   = q * 20;

    float4 ra[5], wa[5], rb[5], wb[5];   // two named reg sets (const-indexed)

    int bb = blockIdx.x;
    ISSUE(bb, 0, ra, wa);
    bool hn = (bb + GRID) < NB;
    if (hn) ISSUE(bb + GRID, 1, rb, wb);

    for (;;) {
        // ---- batch bb in buffer 0 ----
        if (hn) { asm volatile("s_waitcnt vmcnt(15)" ::: "memory"); }
        else    { asm volatile("s_waitcnt vmcnt(0)"  ::: "memory"); }
        BUILD(0, ra, wa);
        POWER_EPI(bb, 0);
        if (!hn) break;

        const bool hn2 = (bb + 2 * GRID) < NB;
        if (hn2) ISSUE(bb + 2 * GRID, 0, ra, wa);

        // ---- batch bb+GRID in buffer 1 ----
        if (hn2) { asm volatile("s_waitcnt vmcnt(15)" ::: "memory"); }
        else     { asm volatile("s_waitcnt vmcnt(0)"  ::: "memory"); }
        BUILD(1, rb, wb);
        POWER_EPI(bb + GRID, 1);
        if (!hn2) break;

        bb += 2 * GRID;
        hn = (bb + GRID) < NB;
        if (hn) ISSUE(bb + GRID, 1, rb, wb);
    }
}

// out[k] = sum_b contrib[b][k]; fixed-order tree -> deterministic.
__global__ __launch_bounds__(256) void reduce_kernel(
    const float* __restrict__ contrib,
    float* __restrict__ out)
{
    __shared__ float s[256];
    const int k = blockIdx.x;
    const int t = threadIdx.x;
    float acc = 0.f;
    for (int b = t; b < NB; b += 256)
        acc += contrib[(size_t)b * NDIM + k];
    s[t] = acc;
    __syncthreads();
    for (int o = 128; o > 0; o >>= 1) {
        if (t < o) s[t] += s[t + o];
        __syncthreads();
    }
    if (t == 0) out[k] = s[0];
}

extern "C" void kernel_launch(void* const* d_in, const int* in_sizes, int n_in,
                              void* d_out, int out_size, void* d_ws, size_t ws_size,
                              hipStream_t stream) {
    const float* x  = (const float*)d_in[0];   // (80,80)
    const float* rz = (const float*)d_in[1];   // (80,80,80,80)
    const float* rc = (const float*)d_in[2];   // (80,80,80,80)
    const float* wt = (const float*)d_in[3];   // (80,80)
    const float* wr = (const float*)d_in[4];   // (80,80,80,80)
    float* out = (float*)d_out;                // (80,)

    float* contrib = (float*)d_ws;             // 6400*80 floats = 2 MB

    hipLaunchKernelGGL(fused_power_kernel, dim3(GRID), dim3(320), 0, stream,
                       x, rz, rc, wt, wr, contrib);
    hipLaunchKernelGGL(reduce_kernel, dim3(NDIM), dim3(256), 0, stream,
                       contrib, out);
}

// Round 8
// 100.648 us; speedup vs baseline: 1.3451x; 1.3451x over previous
//
#include <hip/hip_runtime.h>

#define NDIM 80
#define NB (NDIM * NDIM)   // 6400 batches; also elements per batch matrix
#define TOL 0.01f
#define MAXIT 101          // it 0 = prologue (v0, ev0); 1..100 = reference steps

typedef const __attribute__((address_space(1))) void* gas_ptr;
typedef __attribute__((address_space(3))) void* las_ptr;

// One block per batch b = i*80+j.  (Best-known config: R4, 100.2 us, absmax 0.)
// r_const -> LDS directly (async global_load_lds, no VGPR round trip).
// r_zeros/weights_r -> registers via lane-consecutive dwordx4 (coalesced),
// multiplied into prod[5], then FMA'd into M in place. LDS = 26.3 KB ->
// 6 blocks/CU (30 waves): block A's power loop hides under B..F's staging.
// R5/R6/R7 falsified barrier-drain, reg-MLP, and persistent-pipeline theories:
// all land at the same ~5.2 TB/s fabric operating point (49% L3 hit, single-
// pass streaming). This structure is the simplest at that ceiling.
__global__ __launch_bounds__(320, 8) void fused_power_kernel(
    const float* __restrict__ x,
    const float* __restrict__ r_zeros,
    const float* __restrict__ r_const,
    const float* __restrict__ weights_t,
    const float* __restrict__ weights_r,
    float* __restrict__ contrib)
{
    __shared__ float Ms[NB];    // staged r_const, becomes M in place (25.6 KB)
    __shared__ float v[NDIM];
    __shared__ float av[NDIM];
    __shared__ float red[2];
    __shared__ float sscale;

    const int t    = threadIdx.x;
    const int wv   = t >> 6;     // wave 0..4
    const int lane = t & 63;
    const int b    = blockIdx.x;
    const size_t base = (size_t)b * NB;

    // Async: 25 x 1KB chunks of r_const -> Ms (5 per wave, fire-and-forget).
    #pragma unroll
    for (int c = 0; c < 5; ++c) {
        const int foff = (wv * 5 + c) * 256;   // float offset of this 1KB chunk
        __builtin_amdgcn_global_load_lds((gas_ptr)(r_const + base + foff + lane * 4),
                                         (las_ptr)&Ms[foff], 16, 0, 0);
    }

    // rz*wr into registers; float4 index t + 320u -> coalesced dwordx4.
    float4 prod[5];
    {
        const float4* rz4 = reinterpret_cast<const float4*>(r_zeros + base);
        const float4* wr4 = reinterpret_cast<const float4*>(weights_r + base);
        #pragma unroll
        for (int u = 0; u < 5; ++u) {
            const float4 a = rz4[t + 320 * u];
            const float4 w = wr4[t + 320 * u];
            prod[u].x = w.x * a.x;
            prod[u].y = w.y * a.y;
            prod[u].z = w.z * a.z;
            prod[u].w = w.w * a.w;
        }
    }
    if (t < NDIM) av[t] = 1.0f;   // seed: av = ones, ||av||^2 = 80
    __syncthreads();              // drains vmcnt(0): rc in LDS, prods ready

    // M = rc + wr*rz, in place. b128 RMW, conflict-free.
    #pragma unroll
    for (int u = 0; u < 5; ++u) {
        float4* p4 = reinterpret_cast<float4*>(&Ms[4 * (t + 320 * u)]);
        float4 cc = *p4;
        cc.x += prod[u].x;
        cc.y += prod[u].y;
        cc.z += prod[u].z;
        cc.w += prod[u].w;
        *p4 = cc;
    }
    float n2 = (float)NDIM;
    float ev = 1e30f;             // prologue never "converges"
    __syncthreads();

    const int r  = t >> 2;        // row 0..79
    const int q  = t & 3;         // column quarter
    const int vq = q * 20;
    const float4* Mr4 = reinterpret_cast<const float4*>(&Ms[r * NDIM + vq]);
    const float4* vv4 = reinterpret_cast<const float4*>(&v[vq]);

    for (int it = 0; it < MAXIT; ++it) {
        // v = av / ||av||
        const float inv = rsqrtf(n2);
        if (t < NDIM) v[t] = av[t] * inv;
        __syncthreads();                       // v ready

        // av = M v : 5x ds_read_b128 (M) + 5x b128 broadcast (v), 20 FMA.
        float p = 0.f;
        #pragma unroll
        for (int u = 0; u < 5; ++u) {
            const float4 mm = Mr4[u];
            const float4 xv = vv4[u];
            p = fmaf(mm.x, xv.x, p);
            p = fmaf(mm.y, xv.y, p);
            p = fmaf(mm.z, xv.z, p);
            p = fmaf(mm.w, xv.w, p);
        }
        p += __shfl_xor(p, 1);
        p += __shfl_xor(p, 2);
        if (q == 0) av[r] = p;
        __syncthreads();                       // av ready

        // Fused dual reduction: n2' = ||av||^2, dot = v.av (wave 0 only)
        if (t < 64) {
            float a0 = av[t], v0 = v[t];
            float s2 = a0 * a0;
            float sd = v0 * a0;
            if (t < 16) {
                float a1 = av[t + 64], v1 = v[t + 64];
                s2 = fmaf(a1, a1, s2);
                sd = fmaf(v1, a1, sd);
            }
            #pragma unroll
            for (int o = 32; o > 0; o >>= 1) {
                s2 += __shfl_down(s2, o);
                sd += __shfl_down(sd, o);
            }
            if (t == 0) { red[0] = s2; red[1] = sd; }
        }
        __syncthreads();                       // red ready
        n2 = red[0];
        const float evn = red[1];
        if (fabsf(ev - evn) < TOL) break;      // uniform across block
        ev = evn;
    }

    // contrib[b][k] = v[k] * x[b]*wt[b]*rc[i,j,i,i] / v[i]
    if (t == 0) {
        const int i_idx = b / NDIM;
        const float rc_diag = r_const[base + (size_t)i_idx * NDIM + i_idx];
        sscale = x[b] * weights_t[b] * rc_diag / v[i_idx];
    }
    __syncthreads();
    if (t < NDIM) contrib[(size_t)b * NDIM + t] = v[t] * sscale;
}

// out[k] = sum_b contrib[b][k]; fixed-order tree -> deterministic.
__global__ __launch_bounds__(256) void reduce_kernel(
    const float* __restrict__ contrib,
    float* __restrict__ out)
{
    __shared__ float s[256];
    const int k = blockIdx.x;
    const int t = threadIdx.x;
    float acc = 0.f;
    for (int b = t; b < NB; b += 256)
        acc += contrib[(size_t)b * NDIM + k];
    s[t] = acc;
    __syncthreads();
    for (int o = 128; o > 0; o >>= 1) {
        if (t < o) s[t] += s[t + o];
        __syncthreads();
    }
    if (t == 0) out[k] = s[0];
}

extern "C" void kernel_launch(void* const* d_in, const int* in_sizes, int n_in,
                              void* d_out, int out_size, void* d_ws, size_t ws_size,
                              hipStream_t stream) {
    const float* x  = (const float*)d_in[0];   // (80,80)
    const float* rz = (const float*)d_in[1];   // (80,80,80,80)
    const float* rc = (const float*)d_in[2];   // (80,80,80,80)
    const float* wt = (const float*)d_in[3];   // (80,80)
    const float* wr = (const float*)d_in[4];   // (80,80,80,80)
    float* out = (float*)d_out;                // (80,)

    float* contrib = (float*)d_ws;             // 6400*80 floats = 2 MB

    hipLaunchKernelGGL(fused_power_kernel, dim3(NB), dim3(320), 0, stream,
                       x, rz, rc, wt, wr, contrib);
    hipLaunchKernelGGL(reduce_kernel, dim3(NDIM), dim3(256), 0, stream,
                       contrib, out);
}